// Round 4
// baseline (150.133 us; speedup 1.0000x reference)
//
#include <hip/hip_runtime.h>
#include <hip/hip_bf16.h>

typedef __attribute__((ext_vector_type(8))) short bf16x8;
typedef __attribute__((ext_vector_type(4))) float f32x4;

#define B_DIM 16
#define F_DIM 128
#define N_DIM 20000
#define M_DIM 128
#define NW 32                      // n-tile per block
#define NSUB 2                     // 16-wide subtiles per tile
#define TILES_PER_B 625            // 20000 / 32
#define NBLK (16 * TILES_PER_B)    // 10000
#define MAT_LDS (NW * 128)         // shorts per matrix = 4096 (8192 B)

static __device__ inline unsigned short f2bf(float x) {
    union { float f; unsigned u; } v; v.f = x;
    unsigned r = v.u + 0x7fffu + ((v.u >> 16) & 1u);   // RNE
    return (unsigned short)(r >> 16);
}

// ---------------------------------------------------------------------------
// Kernel 1: fold resize into projections; store bf16 in MFMA fragment order.
// Element (k,f): mt=k>>4, row=k&15, c=f>>5, kk=f&31, lane=(kk>>3)*16+row, j=kk&7
// frag id = (mt*4 + c)*64 + lane, 8 bf16 each.
// ---------------------------------------------------------------------------
__global__ __launch_bounds__(256) void precompute_mats(
    const float* __restrict__ W_rs,   // (128, 384)
    const float* __restrict__ W_e2m,  // (128, 128)
    const float* __restrict__ W_n2m,  // (128, 128)
    unsigned short* __restrict__ wsA,
    unsigned short* __restrict__ wsB)
{
    int idx = blockIdx.x * 256 + threadIdx.x;   // 0..16383
    int k = idx >> 7;
    int f = idx & 127;
    float a = 0.f, b = 0.f;
    for (int m = 0; m < 128; ++m) {
        a += W_rs[k * 384 + m]       * W_e2m[m * 128 + f];
        b += W_rs[k * 384 + 128 + m] * W_n2m[m * 128 + f];
    }
    int mt = k >> 4, row = k & 15;
    int c = f >> 5, kk = f & 31;
    int lane = ((kk >> 3) << 4) | row;
    int j = kk & 7;
    int off = ((mt * 4 + c) * 64 + lane) * 8 + j;
    wsA[off] = f2bf(a);
    wsB[off] = f2bf(b);
}

// ---------------------------------------------------------------------------
// Kernel 2: per-(b,k) bias.
// ---------------------------------------------------------------------------
__global__ __launch_bounds__(128) void precompute_bias(
    const float* __restrict__ W_rs,
    const float* __restrict__ h_v,
    const float* __restrict__ b_e2m,
    const float* __restrict__ b_n2m,
    const float* __restrict__ b_rs,
    const float* __restrict__ W_n2m,
    float* __restrict__ bias)
{
    __shared__ float nv_s[128];
    int b = blockIdx.x;
    int t = threadIdx.x;
    {
        float nv = b_n2m[t];
        for (int f = 0; f < 128; ++f)
            nv += h_v[b * 128 + f] * W_n2m[t * 128 + f];
        nv_s[t] = nv;
    }
    __syncthreads();
    {
        float acc = b_rs[t];
        for (int m = 0; m < 128; ++m) {
            acc += W_rs[t * 384 + m]       * b_e2m[m];
            acc += W_rs[t * 384 + 128 + m] * b_n2m[m];
            acc += W_rs[t * 384 + 256 + m] * nv_s[m];
        }
        bias[b * 128 + t] = acc;
    }
}

// ---------------------------------------------------------------------------
// Kernel 3: main streaming GEMM, LDS-staged, TLP-oriented.
// Block: 256 thr (4 waves), tile = 128 f/k x 32 n of one b. LDS 16 KB ->
// 6 blocks/CU (launch_bounds 256,6) = 24 waves/CU to hide staging latency.
// Wave w owns k rows [32w, 32w+32) (mt = 2w, 2w+1), both n-subtiles.
// LDS per matrix: [nn=32][f=128] bf16, byte ^= (nn&7)<<4 on f-bits.
// ---------------------------------------------------------------------------
__global__ __launch_bounds__(256, 6) void msg_main(
    const float* __restrict__ e_wv,
    const float* __restrict__ h_w,
    const unsigned short* __restrict__ wsA,
    const unsigned short* __restrict__ wsB,
    const float* __restrict__ bias,
    float* __restrict__ out)
{
    __shared__ unsigned short lds[2 * MAT_LDS];   // 16384 B

    int tid = threadIdx.x;
    int w   = tid >> 6;
    int l   = tid & 63;
    // bijective XCD swizzle: 10000 % 8 == 0, 1250 consecutive tiles per XCD
    int blk0 = blockIdx.x;
    int blk  = (blk0 & 7) * (NBLK / 8) + (blk0 >> 3);
    int b   = blk / TILES_PER_B;
    int n0  = (blk - b * TILES_PER_B) * NW;

    const float* eb = e_wv + (size_t)b * (F_DIM * (size_t)N_DIM) + n0;
    const float* wb = h_w  + (size_t)b * (F_DIM * (size_t)N_DIM) + n0;

    // ---- staging: 8 dwordx4 per thread (each wave-instr = 8 full 128B lines)
    // unit u: fp = u*32 + w*8 + (l>>3)  (f-pair row), nq = l&7 (n quad)
    int nq = l & 7;
    int fp0 = 0 * 32 + w * 8 + (l >> 3);
    int fp1 = 1 * 32 + w * 8 + (l >> 3);
    f32x4 ve[2][2], vw[2][2];
    ve[0][0] = *(const f32x4*)(eb + (size_t)(2 * fp0)     * N_DIM + 4 * nq);
    ve[0][1] = *(const f32x4*)(eb + (size_t)(2 * fp0 + 1) * N_DIM + 4 * nq);
    ve[1][0] = *(const f32x4*)(eb + (size_t)(2 * fp1)     * N_DIM + 4 * nq);
    ve[1][1] = *(const f32x4*)(eb + (size_t)(2 * fp1 + 1) * N_DIM + 4 * nq);
    vw[0][0] = *(const f32x4*)(wb + (size_t)(2 * fp0)     * N_DIM + 4 * nq);
    vw[0][1] = *(const f32x4*)(wb + (size_t)(2 * fp0 + 1) * N_DIM + 4 * nq);
    vw[1][0] = *(const f32x4*)(wb + (size_t)(2 * fp1)     * N_DIM + 4 * nq);
    vw[1][1] = *(const f32x4*)(wb + (size_t)(2 * fp1 + 1) * N_DIM + 4 * nq);

    char* ldsc = (char*)lds;
#pragma unroll
    for (int u = 0; u < 2; ++u) {
        int fp = u ? fp1 : fp0;
#pragma unroll
        for (int q = 0; q < 4; ++q) {
            int nn = 4 * nq + q;
            unsigned fo = (unsigned)(fp * 4) ^ (unsigned)((nn & 7) << 4);
            unsigned off = (unsigned)(nn * 256) + fo;
            unsigned pe = (unsigned)f2bf(ve[u][0][q]) | ((unsigned)f2bf(ve[u][1][q]) << 16);
            unsigned pw = (unsigned)f2bf(vw[u][0][q]) | ((unsigned)f2bf(vw[u][1][q]) << 16);
            *(unsigned*)(ldsc + off) = pe;
            *(unsigned*)(ldsc + 2 * MAT_LDS + off) = pw;
        }
    }
    __syncthreads();

    // ---- compute: wave w owns mt = 2w, 2w+1
    int ln = l & 15, g = l >> 4;
    f32x4 acc[2][NSUB];
#pragma unroll
    for (int mtL = 0; mtL < 2; ++mtL)
#pragma unroll
        for (int ns = 0; ns < NSUB; ++ns) acc[mtL][ns] = (f32x4)(0.f);

    const bf16x8* Af = (const bf16x8*)wsA;
    const bf16x8* Bf = (const bf16x8*)wsB;
    const char* ldse = ldsc;
    const char* ldsw = ldsc + 2 * MAT_LDS;
    unsigned rbase = (unsigned)(ln * 256);
    unsigned rx = (unsigned)((ln & 7) << 4);

#pragma unroll
    for (int c = 0; c < 4; ++c) {
        bf16x8 a0 = Af[((2 * w + 0) * 4 + c) * 64 + l];
        bf16x8 a1 = Af[((2 * w + 1) * 4 + c) * 64 + l];
        bf16x8 b0 = Bf[((2 * w + 0) * 4 + c) * 64 + l];
        bf16x8 b1 = Bf[((2 * w + 1) * 4 + c) * 64 + l];
        unsigned fbyte = (unsigned)((c * 32 + g * 8) * 2) ^ rx;
#pragma unroll
        for (int ns = 0; ns < NSUB; ++ns) {
            bf16x8 xe = *(const bf16x8*)(ldse + ns * 4096 + rbase + fbyte);
            bf16x8 xw = *(const bf16x8*)(ldsw + ns * 4096 + rbase + fbyte);
            acc[0][ns] = __builtin_amdgcn_mfma_f32_16x16x32_bf16(a0, xe, acc[0][ns], 0, 0, 0);
            acc[0][ns] = __builtin_amdgcn_mfma_f32_16x16x32_bf16(b0, xw, acc[0][ns], 0, 0, 0);
            acc[1][ns] = __builtin_amdgcn_mfma_f32_16x16x32_bf16(a1, xe, acc[1][ns], 0, 0, 0);
            acc[1][ns] = __builtin_amdgcn_mfma_f32_16x16x32_bf16(b1, xw, acc[1][ns], 0, 0, 0);
        }
    }

    // ---- epilogue: bias + nontemporal store (out never re-read)
    const f32x4* bias4 = (const f32x4*)(bias + b * 128);
    float* O = out + (size_t)b * (M_DIM * (size_t)N_DIM) + n0 + ln;
#pragma unroll
    for (int mtL = 0; mtL < 2; ++mtL) {
        int mt = 2 * w + mtL;
        f32x4 bb = bias4[mt * 4 + g];
#pragma unroll
        for (int ns = 0; ns < NSUB; ++ns) {
#pragma unroll
            for (int r = 0; r < 4; ++r) {
                int k = mt * 16 + g * 4 + r;
                __builtin_nontemporal_store(acc[mtL][ns][r] + bb[r],
                                            O + (size_t)k * N_DIM + ns * 16);
            }
        }
    }
}

extern "C" void kernel_launch(void* const* d_in, const int* in_sizes, int n_in,
                              void* d_out, int out_size, void* d_ws, size_t ws_size,
                              hipStream_t stream) {
    const float* h_w   = (const float*)d_in[0];
    const float* h_v   = (const float*)d_in[1];
    const float* e_wv  = (const float*)d_in[2];
    const float* W_e2m = (const float*)d_in[3];
    const float* b_e2m = (const float*)d_in[4];
    const float* W_n2m = (const float*)d_in[5];
    const float* b_n2m = (const float*)d_in[6];
    const float* W_rs  = (const float*)d_in[7];
    const float* b_rs  = (const float*)d_in[8];
    float* out = (float*)d_out;

    unsigned short* wsA = (unsigned short*)d_ws;                     // 32 KB
    unsigned short* wsB = wsA + 128 * 128;                           // 32 KB
    float* bias = (float*)((char*)d_ws + 65536);                     // 8 KB

    precompute_mats<<<64, 256, 0, stream>>>(W_rs, W_e2m, W_n2m, wsA, wsB);
    precompute_bias<<<16, 128, 0, stream>>>(W_rs, h_v, b_e2m, b_n2m, b_rs, W_n2m, bias);
    msg_main<<<NBLK, 256, 0, stream>>>(e_wv, h_w, wsA, wsB, bias, out);
}

// Round 5
// 139.670 us; speedup vs baseline: 1.0749x; 1.0749x over previous
//
#include <hip/hip_runtime.h>
#include <hip/hip_bf16.h>

typedef __attribute__((ext_vector_type(8))) short bf16x8;
typedef __attribute__((ext_vector_type(4))) float f32x4;

#define B_DIM 16
#define F_DIM 128
#define N_DIM 20000
#define M_DIM 128
#define NW 32                      // n-tile per block
#define NSUB 2                     // 16-wide subtiles
#define TILES_PER_B 625            // 20000 / 32
#define NBLK (16 * TILES_PER_B)    // 10000
#define LDS_F32_MAT 16384          // 128 f x 32 n x 4B
#define LDS_BF16_OFF 32768
#define LDS_BF16_MAT 8192          // 32 nn x 128 f x 2B

#define AS1 __attribute__((address_space(1)))
#define AS3 __attribute__((address_space(3)))

static __device__ inline unsigned short f2bf(float x) {
    union { float f; unsigned u; } v; v.f = x;
    unsigned r = v.u + 0x7fffu + ((v.u >> 16) & 1u);   // RNE
    return (unsigned short)(r >> 16);
}

// ---------------------------------------------------------------------------
// Kernel 1: fold resize into projections; store bf16 in MFMA fragment order.
// ---------------------------------------------------------------------------
__global__ __launch_bounds__(256) void precompute_mats(
    const float* __restrict__ W_rs,   // (128, 384)
    const float* __restrict__ W_e2m,  // (128, 128)
    const float* __restrict__ W_n2m,  // (128, 128)
    unsigned short* __restrict__ wsA,
    unsigned short* __restrict__ wsB)
{
    int idx = blockIdx.x * 256 + threadIdx.x;   // 0..16383
    int k = idx >> 7;
    int f = idx & 127;
    float a = 0.f, b = 0.f;
    for (int m = 0; m < 128; ++m) {
        a += W_rs[k * 384 + m]       * W_e2m[m * 128 + f];
        b += W_rs[k * 384 + 128 + m] * W_n2m[m * 128 + f];
    }
    int mt = k >> 4, row = k & 15;
    int c = f >> 5, kk = f & 31;
    int lane = ((kk >> 3) << 4) | row;
    int j = kk & 7;
    int off = ((mt * 4 + c) * 64 + lane) * 8 + j;
    wsA[off] = f2bf(a);
    wsB[off] = f2bf(b);
}

// ---------------------------------------------------------------------------
// Kernel 2: per-(b,k) bias.
// ---------------------------------------------------------------------------
__global__ __launch_bounds__(128) void precompute_bias(
    const float* __restrict__ W_rs,
    const float* __restrict__ h_v,
    const float* __restrict__ b_e2m,
    const float* __restrict__ b_n2m,
    const float* __restrict__ b_rs,
    const float* __restrict__ W_n2m,
    float* __restrict__ bias)
{
    __shared__ float nv_s[128];
    int b = blockIdx.x;
    int t = threadIdx.x;
    {
        float nv = b_n2m[t];
        for (int f = 0; f < 128; ++f)
            nv += h_v[b * 128 + f] * W_n2m[t * 128 + f];
        nv_s[t] = nv;
    }
    __syncthreads();
    {
        float acc = b_rs[t];
        for (int m = 0; m < 128; ++m) {
            acc += W_rs[t * 384 + m]       * b_e2m[m];
            acc += W_rs[t * 384 + 128 + m] * b_n2m[m];
            acc += W_rs[t * 384 + 256 + m] * nv_s[m];
        }
        bias[b * 128 + t] = acc;
    }
}

// ---------------------------------------------------------------------------
// Kernel 3: main streaming GEMM.
// Phase 1: global_load_lds DMA of 128x32 f32 of both mats (fire-and-forget,
//          zero dest VGPRs; source quad-order pre-swizzled q = p ^ (f&7)).
// Phase 2: f32 -> packed bf16 transpose into [nn=32][f=128] XOR-swizzled.
// Phase 3: MFMA (wave w owns k rows [32w,32w+32)).
// Stores: plain dword (L2 merges 64B halves; NT was a measured regression).
// ---------------------------------------------------------------------------
__global__ __launch_bounds__(256) void msg_main(
    const float* __restrict__ e_wv,
    const float* __restrict__ h_w,
    const unsigned short* __restrict__ wsA,
    const unsigned short* __restrict__ wsB,
    const float* __restrict__ bias,
    float* __restrict__ out)
{
    __shared__ __align__(16) unsigned char smem[49152];

    int tid = threadIdx.x;
    int w   = tid >> 6;
    int l   = tid & 63;
    // bijective XCD swizzle: 10000 % 8 == 0, 1250 consecutive tiles per XCD
    int blk0 = blockIdx.x;
    int blk  = (blk0 & 7) * (NBLK / 8) + (blk0 >> 3);
    int b   = blk / TILES_PER_B;
    int n0  = (blk - b * TILES_PER_B) * NW;

    const float* eb = e_wv + (size_t)b * (F_DIM * (size_t)N_DIM) + n0;
    const float* wb = h_w  + (size_t)b * (F_DIM * (size_t)N_DIM) + n0;

    // ---- Phase 1: async DMA. Per wave per mat: 4 instrs x 1KB (8 f-rows).
    // LDS [f][p] (p = lane&7) holds global quad q = p ^ (f&7); f&7 == l>>3.
    {
        int qsw = ((l & 7) ^ (l >> 3)) * 4;   // pre-swizzled source n offset
        int fl  = l >> 3;
#pragma unroll
        for (int i = 0; i < 4; ++i) {
            int f_base = i * 32 + w * 8;
            unsigned char* ld_e = smem + f_base * 128;
            unsigned char* ld_w = smem + LDS_F32_MAT + f_base * 128;
            const float* ge = eb + (size_t)(f_base + fl) * N_DIM + qsw;
            const float* gw = wb + (size_t)(f_base + fl) * N_DIM + qsw;
            __builtin_amdgcn_global_load_lds((const AS1 unsigned*)ge, (AS3 unsigned*)ld_e, 16, 0, 0);
            __builtin_amdgcn_global_load_lds((const AS1 unsigned*)gw, (AS3 unsigned*)ld_w, 16, 0, 0);
        }
    }
    __syncthreads();   // drains vmcnt

    // ---- Phase 2: transform. Threads 0-127: mat e; 128-255: mat w.
    {
        int m    = tid >> 7;
        int u    = tid & 127;
        int fp   = u >> 1;        // f-pair 0..63
        int half = u & 1;
        const unsigned char* fsrc = smem + m * LDS_F32_MAT;
        unsigned char* bdst = smem + LDS_BF16_OFF + m * LDS_BF16_MAT;
        int f0 = 2 * fp, f1 = 2 * fp + 1;
        int x0 = f0 & 7, x1 = f1 & 7;
#pragma unroll
        for (int j = 0; j < 4; ++j) {
            int q = half * 4 + j;
            f32x4 a = *(const f32x4*)(fsrc + f0 * 128 + (q ^ x0) * 16);
            f32x4 c = *(const f32x4*)(fsrc + f1 * 128 + (q ^ x1) * 16);
#pragma unroll
            for (int e = 0; e < 4; ++e) {
                int n = q * 4 + e;
                unsigned pk = (unsigned)f2bf(a[e]) | ((unsigned)f2bf(c[e]) << 16);
                unsigned off = (unsigned)(n * 256) +
                               ((unsigned)(fp * 4) ^ (unsigned)((n & 7) << 4));
                *(unsigned*)(bdst + off) = pk;
            }
        }
    }
    __syncthreads();

    // ---- Phase 3: compute. Wave w owns mt = 2w, 2w+1.
    int ln = l & 15, g = l >> 4;
    f32x4 acc[2][NSUB];
#pragma unroll
    for (int mtL = 0; mtL < 2; ++mtL)
#pragma unroll
        for (int ns = 0; ns < NSUB; ++ns) acc[mtL][ns] = (f32x4)(0.f);

    const bf16x8* Af = (const bf16x8*)wsA;
    const bf16x8* Bf = (const bf16x8*)wsB;
    const unsigned char* ldse = smem + LDS_BF16_OFF;
    const unsigned char* ldsw = smem + LDS_BF16_OFF + LDS_BF16_MAT;
    unsigned rbase = (unsigned)(ln * 256);
    unsigned rx = (unsigned)((ln & 7) << 4);

#pragma unroll
    for (int c = 0; c < 4; ++c) {
        bf16x8 a0 = Af[((2 * w + 0) * 4 + c) * 64 + l];
        bf16x8 a1 = Af[((2 * w + 1) * 4 + c) * 64 + l];
        bf16x8 b0 = Bf[((2 * w + 0) * 4 + c) * 64 + l];
        bf16x8 b1 = Bf[((2 * w + 1) * 4 + c) * 64 + l];
        unsigned fbyte = (unsigned)((c * 32 + g * 8) * 2) ^ rx;
#pragma unroll
        for (int ns = 0; ns < NSUB; ++ns) {
            bf16x8 xe = *(const bf16x8*)(ldse + ns * 4096 + rbase + fbyte);
            bf16x8 xw = *(const bf16x8*)(ldsw + ns * 4096 + rbase + fbyte);
            acc[0][ns] = __builtin_amdgcn_mfma_f32_16x16x32_bf16(a0, xe, acc[0][ns], 0, 0, 0);
            acc[0][ns] = __builtin_amdgcn_mfma_f32_16x16x32_bf16(b0, xw, acc[0][ns], 0, 0, 0);
            acc[1][ns] = __builtin_amdgcn_mfma_f32_16x16x32_bf16(a1, xe, acc[1][ns], 0, 0, 0);
            acc[1][ns] = __builtin_amdgcn_mfma_f32_16x16x32_bf16(b1, xw, acc[1][ns], 0, 0, 0);
        }
    }

    // ---- epilogue: bias + plain stores
    const f32x4* bias4 = (const f32x4*)(bias + b * 128);
    float* O = out + (size_t)b * (M_DIM * (size_t)N_DIM) + n0 + ln;
#pragma unroll
    for (int mtL = 0; mtL < 2; ++mtL) {
        int mt = 2 * w + mtL;
        f32x4 bb = bias4[mt * 4 + g];
#pragma unroll
        for (int ns = 0; ns < NSUB; ++ns) {
#pragma unroll
            for (int r = 0; r < 4; ++r) {
                int k = mt * 16 + g * 4 + r;
                O[(size_t)k * N_DIM + ns * 16] = acc[mtL][ns][r] + bb[r];
            }
        }
    }
}

extern "C" void kernel_launch(void* const* d_in, const int* in_sizes, int n_in,
                              void* d_out, int out_size, void* d_ws, size_t ws_size,
                              hipStream_t stream) {
    const float* h_w   = (const float*)d_in[0];
    const float* h_v   = (const float*)d_in[1];
    const float* e_wv  = (const float*)d_in[2];
    const float* W_e2m = (const float*)d_in[3];
    const float* b_e2m = (const float*)d_in[4];
    const float* W_n2m = (const float*)d_in[5];
    const float* b_n2m = (const float*)d_in[6];
    const float* W_rs  = (const float*)d_in[7];
    const float* b_rs  = (const float*)d_in[8];
    float* out = (float*)d_out;

    unsigned short* wsA = (unsigned short*)d_ws;                     // 32 KB
    unsigned short* wsB = wsA + 128 * 128;                           // 32 KB
    float* bias = (float*)((char*)d_ws + 65536);                     // 8 KB

    precompute_mats<<<64, 256, 0, stream>>>(W_rs, W_e2m, W_n2m, wsA, wsB);
    precompute_bias<<<16, 128, 0, stream>>>(W_rs, h_v, b_e2m, b_n2m, b_rs, W_n2m, bias);
    msg_main<<<NBLK, 256, 0, stream>>>(e_wv, h_w, wsA, wsB, bias, out);
}

// Round 6
// 134.388 us; speedup vs baseline: 1.1172x; 1.0393x over previous
//
#include <hip/hip_runtime.h>
#include <hip/hip_bf16.h>

typedef __attribute__((ext_vector_type(8))) short bf16x8;
typedef __attribute__((ext_vector_type(4))) float f32x4;

#define F_DIM 128
#define N_DIM 20000
#define M_DIM 128
#define NW 32                 // n per tile
#define TILES_PER_B 625       // 20000/32
#define NT 20                 // tiles per block
#define GRID 500              // 500*20 = 10000 tiles
#define F32_TILE 32768        // per-tile f32 stage: 2 mats * 128f * 32n * 4B
#define F32_MAT 16384
#define BF16_OFF 65536        // after 2 f32 buffers
#define BF16_MAT 8192

#define AS1 __attribute__((address_space(1)))
#define AS3 __attribute__((address_space(3)))

static __device__ inline unsigned short f2bf(float x) {
    union { float f; unsigned u; } v; v.f = x;
    unsigned r = v.u + 0x7fffu + ((v.u >> 16) & 1u);   // RNE
    return (unsigned short)(r >> 16);
}

// ---------------------------------------------------------------------------
// Kernel 1: fold resize into projections; bf16 in MFMA fragment order.
// ---------------------------------------------------------------------------
__global__ __launch_bounds__(256) void precompute_mats(
    const float* __restrict__ W_rs,   // (128, 384)
    const float* __restrict__ W_e2m,  // (128, 128)
    const float* __restrict__ W_n2m,  // (128, 128)
    unsigned short* __restrict__ wsA,
    unsigned short* __restrict__ wsB)
{
    int idx = blockIdx.x * 256 + threadIdx.x;   // 0..16383
    int k = idx >> 7;
    int f = idx & 127;
    float a = 0.f, b = 0.f;
    for (int m = 0; m < 128; ++m) {
        a += W_rs[k * 384 + m]       * W_e2m[m * 128 + f];
        b += W_rs[k * 384 + 128 + m] * W_n2m[m * 128 + f];
    }
    int mt = k >> 4, row = k & 15;
    int c = f >> 5, kk = f & 31;
    int lane = ((kk >> 3) << 4) | row;
    int j = kk & 7;
    int off = ((mt * 4 + c) * 64 + lane) * 8 + j;
    wsA[off] = f2bf(a);
    wsB[off] = f2bf(b);
}

// ---------------------------------------------------------------------------
// Kernel 2: per-(b,k) bias.
// ---------------------------------------------------------------------------
__global__ __launch_bounds__(128) void precompute_bias(
    const float* __restrict__ W_rs,
    const float* __restrict__ h_v,
    const float* __restrict__ b_e2m,
    const float* __restrict__ b_n2m,
    const float* __restrict__ b_rs,
    const float* __restrict__ W_n2m,
    float* __restrict__ bias)
{
    __shared__ float nv_s[128];
    int b = blockIdx.x;
    int t = threadIdx.x;
    {
        float nv = b_n2m[t];
        for (int f = 0; f < 128; ++f)
            nv += h_v[b * 128 + f] * W_n2m[t * 128 + f];
        nv_s[t] = nv;
    }
    __syncthreads();
    {
        float acc = b_rs[t];
        for (int m = 0; m < 128; ++m) {
            acc += W_rs[t * 384 + m]       * b_e2m[m];
            acc += W_rs[t * 384 + 128 + m] * b_n2m[m];
            acc += W_rs[t * 384 + 256 + m] * nv_s[m];
        }
        bias[b * 128 + t] = acc;
    }
}

// ---------------------------------------------------------------------------
// Kernel 3: persistent pipelined streaming GEMM.
// 500 blocks x 20 tiles. Per iter: issue DMA(t+2) -> compute(t) ->
// vmcnt(8) [t+1 done, t+2 in flight] -> barrier -> transform(t+1) ->
// barrier -> store(t). Counted vmcnt keeps 2 tiles (64KB) in flight/block.
// f32 stage slot swizzle g(f)=(f^(f>>3))&7 (source-preswizzled, read with
// same involution). bf16 layout unchanged from verified rounds.
// ---------------------------------------------------------------------------
__global__ __launch_bounds__(256, 2) void msg_main(
    const float* __restrict__ e_wv,
    const float* __restrict__ h_w,
    const unsigned short* __restrict__ wsA,
    const unsigned short* __restrict__ wsB,
    const float* __restrict__ bias,
    float* __restrict__ out)
{
    __shared__ __align__(16) unsigned char smem[81920];   // 2x32KB f32 + 16KB bf16

    int tid = threadIdx.x;
    int w   = tid >> 6;
    int l   = tid & 63;
    unsigned base = (unsigned)blockIdx.x * NT;

    // ---- preload weight fragments into registers (loop-invariant, 64 VGPR)
    const bf16x8* Af = (const bf16x8*)wsA;
    const bf16x8* Bf = (const bf16x8*)wsB;
    bf16x8 A0[4], A1[4], B0[4], B1[4];
#pragma unroll
    for (int c = 0; c < 4; ++c) {
        A0[c] = Af[((2 * w + 0) * 4 + c) * 64 + l];
        A1[c] = Af[((2 * w + 1) * 4 + c) * 64 + l];
        B0[c] = Bf[((2 * w + 0) * 4 + c) * 64 + l];
        B1[c] = Bf[((2 * w + 1) * 4 + c) * 64 + l];
    }

    int fl = l >> 3, p = l & 7;
    auto issue_dma = [&](unsigned tau, unsigned bufsel) {
        unsigned bb = tau / TILES_PER_B;
        unsigned n0 = (tau - bb * TILES_PER_B) * NW;
        const float* eb = e_wv + (size_t)bb * (F_DIM * (size_t)N_DIM) + n0;
        const float* wp = h_w  + (size_t)bb * (F_DIM * (size_t)N_DIM) + n0;
        unsigned char* buf = smem + bufsel * F32_TILE;
#pragma unroll
        for (int i = 0; i < 4; ++i) {
            int fb = i * 32 + w * 8;
            int f  = fb + fl;
            int g  = (f ^ (f >> 3)) & 7;
            int col = (p ^ g) << 2;
            __builtin_amdgcn_global_load_lds(
                (const AS1 unsigned*)(eb + (size_t)f * N_DIM + col),
                (AS3 unsigned*)(buf + fb * 128), 16, 0, 0);
            __builtin_amdgcn_global_load_lds(
                (const AS1 unsigned*)(wp + (size_t)f * N_DIM + col),
                (AS3 unsigned*)(buf + F32_MAT + fb * 128), 16, 0, 0);
        }
    };

    auto transform = [&](unsigned bufsel) {
        const unsigned char* fsrc = smem + bufsel * F32_TILE + (tid >> 7) * F32_MAT;
        unsigned char* bdst = smem + BF16_OFF + (tid >> 7) * BF16_MAT;
        int u = tid & 127;
        int fp = u >> 1, half = u & 1;
        int f0 = 2 * fp, f1 = 2 * fp + 1;
        int g0 = (f0 ^ (f0 >> 3)) & 7, g1 = (f1 ^ (f1 >> 3)) & 7;
#pragma unroll
        for (int j = 0; j < 4; ++j) {
            int q = half * 4 + j;
            f32x4 a = *(const f32x4*)(fsrc + f0 * 128 + ((q ^ g0) << 4));
            f32x4 c = *(const f32x4*)(fsrc + f1 * 128 + ((q ^ g1) << 4));
#pragma unroll
            for (int e = 0; e < 4; ++e) {
                int n = q * 4 + e;
                unsigned pk = (unsigned)f2bf(a[e]) | ((unsigned)f2bf(c[e]) << 16);
                unsigned off = (unsigned)(n * 256) +
                               (((unsigned)(fp * 4)) ^ ((unsigned)((n & 7) << 4)));
                *(unsigned*)(bdst + off) = pk;
            }
        }
    };

    // ---- prologue: DMA tiles 0,1; transform tile 0
    issue_dma(base + 0, 0);
    issue_dma(base + 1, 1);
    asm volatile("s_waitcnt vmcnt(8)" ::: "memory");   // weights + DMA(0) done
    __builtin_amdgcn_s_barrier();
    transform(0);
    asm volatile("s_waitcnt lgkmcnt(0)" ::: "memory");
    __builtin_amdgcn_s_barrier();

    int ln = l & 15, g = l >> 4;
    unsigned rbase = (unsigned)(ln * 256);
    unsigned rx = (unsigned)((ln & 7) << 4);
    const unsigned char* ldse = smem + BF16_OFF;
    const unsigned char* ldsw = smem + BF16_OFF + BF16_MAT;

#pragma unroll 1
    for (int t = 0; t < NT; ++t) {
        unsigned tau = base + t;
        unsigned bb = tau / TILES_PER_B;
        unsigned n0 = (tau - bb * TILES_PER_B) * NW;

        // bias for this tile (L2-hit; drained by the counted wait below)
        const float* bp = bias + bb * 128;
        f32x4 bv0 = *(const f32x4*)(bp + (2 * w + 0) * 16 + g * 4);
        f32x4 bv1 = *(const f32x4*)(bp + (2 * w + 1) * 16 + g * 4);

        // issue DMA for tile t+2 into buf[t&1] (wrap keeps counts uniform)
        int t2 = t + 2; if (t2 >= NT) t2 -= NT;
        issue_dma(base + t2, (unsigned)(t & 1));

        // compute(t) from bf16 buffer
        f32x4 acc[2][2];
#pragma unroll
        for (int mtL = 0; mtL < 2; ++mtL)
#pragma unroll
            for (int ns = 0; ns < 2; ++ns) acc[mtL][ns] = (f32x4)(0.f);
#pragma unroll
        for (int c = 0; c < 4; ++c) {
            unsigned fbyte = (unsigned)((c * 32 + g * 8) * 2) ^ rx;
#pragma unroll
            for (int ns = 0; ns < 2; ++ns) {
                bf16x8 xe = *(const bf16x8*)(ldse + ns * 4096 + rbase + fbyte);
                bf16x8 xw = *(const bf16x8*)(ldsw + ns * 4096 + rbase + fbyte);
                acc[0][ns] = __builtin_amdgcn_mfma_f32_16x16x32_bf16(A0[c], xe, acc[0][ns], 0, 0, 0);
                acc[0][ns] = __builtin_amdgcn_mfma_f32_16x16x32_bf16(B0[c], xw, acc[0][ns], 0, 0, 0);
                acc[1][ns] = __builtin_amdgcn_mfma_f32_16x16x32_bf16(A1[c], xe, acc[1][ns], 0, 0, 0);
                acc[1][ns] = __builtin_amdgcn_mfma_f32_16x16x32_bf16(B1[c], xw, acc[1][ns], 0, 0, 0);
            }
        }

        // counted wait: leaves only DMA(t+2)'s 8 ops outstanding => t+1 ready
        asm volatile("s_waitcnt vmcnt(8)" ::: "memory");
        asm volatile("s_waitcnt lgkmcnt(0)" ::: "memory");
        __builtin_amdgcn_s_barrier();

        if (t < NT - 1) transform((unsigned)((t + 1) & 1));
        asm volatile("s_waitcnt lgkmcnt(0)" ::: "memory");
        __builtin_amdgcn_s_barrier();

        // store(t): bias + plain dword stores (L2 merges 64B halves)
        float* O = out + (size_t)bb * (M_DIM * (size_t)N_DIM) + n0 + ln;
#pragma unroll
        for (int mtL = 0; mtL < 2; ++mtL) {
            f32x4 bv = mtL ? bv1 : bv0;
            int mt = 2 * w + mtL;
#pragma unroll
            for (int ns = 0; ns < 2; ++ns)
#pragma unroll
                for (int r = 0; r < 4; ++r)
                    O[(size_t)(mt * 16 + g * 4 + r) * N_DIM + ns * 16] =
                        acc[mtL][ns][r] + bv[r];
        }
    }

    // drain outstanding DMAs before endpgm (LDS reuse hazard)
    asm volatile("s_waitcnt vmcnt(0)" ::: "memory");
}

extern "C" void kernel_launch(void* const* d_in, const int* in_sizes, int n_in,
                              void* d_out, int out_size, void* d_ws, size_t ws_size,
                              hipStream_t stream) {
    const float* h_w   = (const float*)d_in[0];
    const float* h_v   = (const float*)d_in[1];
    const float* e_wv  = (const float*)d_in[2];
    const float* W_e2m = (const float*)d_in[3];
    const float* b_e2m = (const float*)d_in[4];
    const float* W_n2m = (const float*)d_in[5];
    const float* b_n2m = (const float*)d_in[6];
    const float* W_rs  = (const float*)d_in[7];
    const float* b_rs  = (const float*)d_in[8];
    float* out = (float*)d_out;

    unsigned short* wsA = (unsigned short*)d_ws;                     // 32 KB
    unsigned short* wsB = wsA + 128 * 128;                           // 32 KB
    float* bias = (float*)((char*)d_ws + 65536);                     // 8 KB

    precompute_mats<<<64, 256, 0, stream>>>(W_rs, W_e2m, W_n2m, wsA, wsB);
    precompute_bias<<<16, 128, 0, stream>>>(W_rs, h_v, b_e2m, b_n2m, b_rs, W_n2m, bias);
    msg_main<<<GRID, 256, 0, stream>>>(e_wv, h_w, wsA, wsB, bias, out);
}